// Round 1
// baseline (1572.338 us; speedup 1.0000x reference)
//
#include <hip/hip_runtime.h>

#define N_NODES 50000
#define N_EDGES 800000
#define C_INF   32
#define C_OUTF  32
#define K_BR    8

// ---------------- workspace layout (bytes) ----------------
// sum        : N*32 floats  @ 0          (6,400,000)
// cntNode    : N   floats   @ 6,400,000  (200,000)
// bucketCnt  : 8 ints       @ 6,600,000
// bucketCur  : 8 ints       @ 6,600,032
// perm       : E+512 ints   @ 6,600,064  (3,202,048)
// W1T        : 9216 floats  @ 9,802,112  (36,864)   [k][o][c]
// W2T        : 8192 floats  @ 9,838,976  (32,768)   [k][g][o]
// total: 9,871,744 bytes

__device__ __forceinline__ int branch_idx(float dx, float dy) {
    return (dx > 0.0f ? 1 : 0) + (dy > 0.0f ? 2 : 0) +
           ((fabsf(dx) - fabsf(dy)) > 0.0f ? 4 : 0);
}

__global__ void transpose_kernel(const float* __restrict__ W1, const float* __restrict__ W2,
                                 float* __restrict__ W1T, float* __restrict__ W2T) {
    int t = blockIdx.x * blockDim.x + threadIdx.x;
    if (t < K_BR * 36 * 32) {
        int k = t / 1152, r = t % 1152;
        int c = r / 32, o = r % 32;
        W1T[k * 1152 + o * 36 + c] = W1[t];
    } else {
        int u = t - K_BR * 36 * 32;  // grid sized exactly, u < 8192
        int k = u / 1024, r = u % 1024;
        int o = r / 32, g = r % 32;
        W2T[k * 1024 + g * 32 + o] = W2[u];
    }
}

__global__ void count_kernel(const int* __restrict__ ei, const float* __restrict__ pos,
                             int* __restrict__ bucketCnt, float* __restrict__ cntNode) {
    __shared__ int h[K_BR];
    int t = threadIdx.x;
    if (t < K_BR) h[t] = 0;
    __syncthreads();
    int e = blockIdx.x * blockDim.x + t;
    if (e < N_EDGES) {
        int s = ei[e], d = ei[N_EDGES + e];
        float dx = pos[2 * s] - pos[2 * d];
        float dy = pos[2 * s + 1] - pos[2 * d + 1];
        atomicAdd(&h[branch_idx(dx, dy)], 1);
        unsafeAtomicAdd(&cntNode[d], 1.0f);
    }
    __syncthreads();
    if (t < K_BR && h[t] > 0) atomicAdd(&bucketCnt[t], h[t]);
}

__global__ void offsets_kernel(const int* __restrict__ bucketCnt, int* __restrict__ cursor) {
    int off = 0;
    for (int k = 0; k < K_BR; ++k) {
        cursor[k] = off;
        off = (off + bucketCnt[k] + 63) & ~63;  // 64-align next bucket start
    }
}

__global__ void scatter_kernel(const int* __restrict__ ei, const float* __restrict__ pos,
                               int* __restrict__ cursor, int* __restrict__ perm) {
    __shared__ int h[K_BR];
    __shared__ int base[K_BR];
    int t = threadIdx.x;
    if (t < K_BR) h[t] = 0;
    __syncthreads();
    int e = blockIdx.x * blockDim.x + t;
    int idx = 0, rank = 0;
    bool valid = e < N_EDGES;
    if (valid) {
        int s = ei[e], d = ei[N_EDGES + e];
        float dx = pos[2 * s] - pos[2 * d];
        float dy = pos[2 * s + 1] - pos[2 * d + 1];
        idx = branch_idx(dx, dy);
        rank = atomicAdd(&h[idx], 1);
    }
    __syncthreads();
    if (t < K_BR) base[t] = (h[t] > 0) ? atomicAdd(&cursor[t], h[t]) : 0;
    __syncthreads();
    if (valid) perm[base[idx] + rank] = e | (idx << 24);
}

__global__ void __launch_bounds__(256) mlp_kernel(
    const int* __restrict__ perm, const int* __restrict__ ei,
    const float* __restrict__ x, const float* __restrict__ ea,
    const float* __restrict__ ew,
    const float* __restrict__ W1T, const float* __restrict__ b1,
    const float* __restrict__ W2T, const float* __restrict__ b2,
    float* __restrict__ sum) {
    int t = blockIdx.x * blockDim.x + threadIdx.x;
    int p = perm[t];
    // bucket spans are 64-aligned and filled contiguously from the start, so
    // if lane 0 of a wave is padding (-1), the whole wave is padding.
    int p0 = __builtin_amdgcn_readfirstlane(p);
    if (p0 < 0) return;
    int k = (p0 >> 24) & 7;  // wave-uniform branch id -> weights become s_loads
    bool valid = p >= 0;
    int e = valid ? (p & 0xFFFFFF) : (p0 & 0xFFFFFF);

    int s = ei[e];
    int d = ei[N_EDGES + e];

    float m[36];
    const float4* xj = (const float4*)(x + 32 * (size_t)s);
    const float4* xi = (const float4*)(x + 32 * (size_t)d);
#pragma unroll
    for (int q = 0; q < 8; ++q) {
        float4 a = xj[q], b = xi[q];
        m[4 * q + 0] = a.x - b.x;
        m[4 * q + 1] = a.y - b.y;
        m[4 * q + 2] = a.z - b.z;
        m[4 * q + 3] = a.w - b.w;
    }
    float4 eav = ((const float4*)ea)[e];
    m[32] = eav.x; m[33] = eav.y; m[34] = eav.z; m[35] = eav.w;
    float w = ew[e];

    const float* w1  = W1T + k * (32 * 36);
    const float* bb1 = b1 + k * 32;
    float h[32];
#pragma unroll
    for (int o = 0; o < 32; ++o) {
        float acc = bb1[o];
#pragma unroll
        for (int c = 0; c < 36; ++c) acc = fmaf(m[c], w1[o * 36 + c], acc);
        h[o] = fmaxf(acc, 0.0f);
    }

    const float* w2  = W2T + k * 1024;
    const float* bb2 = b2 + k * 32;
    float* srow = sum + 32 * (size_t)d;
#pragma unroll
    for (int g = 0; g < 32; ++g) {
        float acc = bb2[g];
#pragma unroll
        for (int o = 0; o < 32; ++o) acc = fmaf(h[o], w2[g * 32 + o], acc);
        float f = fmaxf(acc, 0.0f) * w;
        if (valid) unsafeAtomicAdd(&srow[g], f);
    }
}

__global__ void final_kernel(const float* __restrict__ sum, const float* __restrict__ cnt,
                             const float* __restrict__ x, const float* __restrict__ Wr,
                             const float* __restrict__ br, float* __restrict__ out) {
    int t = blockIdx.x * blockDim.x + threadIdx.x;
    if (t >= N_NODES * C_OUTF) return;
    int n = t >> 5, o = t & 31;
    float inv = 1.0f / fmaxf(cnt[n], 1.0f);
    float acc = sum[t] * inv + br[o];
    const float* xr = x + 32 * (size_t)n;
#pragma unroll
    for (int c = 0; c < 32; ++c) acc = fmaf(xr[c], Wr[c * 32 + o], acc);
    out[t] = acc;
}

extern "C" void kernel_launch(void* const* d_in, const int* in_sizes, int n_in,
                              void* d_out, int out_size, void* d_ws, size_t ws_size,
                              hipStream_t stream) {
    const float* x   = (const float*)d_in[0];
    const float* pos = (const float*)d_in[1];
    const int*   ei  = (const int*)d_in[2];
    const float* ea  = (const float*)d_in[3];
    const float* ew  = (const float*)d_in[4];
    const float* W1  = (const float*)d_in[5];
    const float* b1  = (const float*)d_in[6];
    const float* W2  = (const float*)d_in[7];
    const float* b2  = (const float*)d_in[8];
    const float* Wr  = (const float*)d_in[9];
    const float* br  = (const float*)d_in[10];
    float* out = (float*)d_out;

    char* ws = (char*)d_ws;
    float* sum       = (float*)(ws + 0);
    float* cntNode   = (float*)(ws + 6400000);
    int*   bucketCnt = (int*)(ws + 6600000);
    int*   bucketCur = (int*)(ws + 6600032);
    int*   perm      = (int*)(ws + 6600064);
    float* W1T       = (float*)(ws + 9802112);
    float* W2T       = (float*)(ws + 9838976);

    hipMemsetAsync(sum, 0, 6600000, stream);                    // sum + cntNode
    hipMemsetAsync(bucketCnt, 0, 64, stream);                   // counts + cursors
    hipMemsetAsync(perm, 0xFF, (N_EDGES + 512) * 4, stream);    // all -1

    transpose_kernel<<<68, 256, 0, stream>>>(W1, W2, W1T, W2T);
    count_kernel<<<(N_EDGES + 255) / 256, 256, 0, stream>>>(ei, pos, bucketCnt, cntNode);
    offsets_kernel<<<1, 1, 0, stream>>>(bucketCnt, bucketCur);
    scatter_kernel<<<(N_EDGES + 255) / 256, 256, 0, stream>>>(ei, pos, bucketCur, perm);
    mlp_kernel<<<(N_EDGES + 512) / 256, 256, 0, stream>>>(perm, ei, x, ea, ew,
                                                          W1T, b1, W2T, b2, sum);
    final_kernel<<<(N_NODES * C_OUTF + 255) / 256, 256, 0, stream>>>(sum, cntNode, x, Wr, br, out);
}

// Round 2
// 363.547 us; speedup vs baseline: 4.3250x; 4.3250x over previous
//
#include <hip/hip_runtime.h>

#define N_NODES 50000
#define N_EDGES 800000
#define K_BR    8
#define SCAN_BLOCKS 196  // ceil(50000/256)

__device__ __forceinline__ int branch_idx(float dx, float dy) {
    return (dx > 0.0f ? 1 : 0) + (dy > 0.0f ? 2 : 0) +
           ((fabsf(dx) - fabsf(dy)) > 0.0f ? 4 : 0);
}

__global__ void transpose_kernel(const float* __restrict__ W1, const float* __restrict__ W2,
                                 float* __restrict__ W1T, float* __restrict__ W2T) {
    int t = blockIdx.x * blockDim.x + threadIdx.x;
    if (t < K_BR * 36 * 32) {
        int k = t / 1152, r = t % 1152;
        int c = r / 32, o = r % 32;
        W1T[k * 1152 + o * 36 + c] = W1[t];
    } else {
        int u = t - K_BR * 36 * 32;  // grid sized exactly, u < 8192
        int k = u / 1024, r = u % 1024;
        int o = r / 32, g = r % 32;
        W2T[k * 1024 + g * 32 + o] = W2[u];
    }
}

__global__ void count_kernel(const int* __restrict__ ei, const float* __restrict__ pos,
                             int* __restrict__ bucketCnt, int* __restrict__ deg) {
    __shared__ int h[K_BR];
    int t = threadIdx.x;
    if (t < K_BR) h[t] = 0;
    __syncthreads();
    int e = blockIdx.x * blockDim.x + t;
    if (e < N_EDGES) {
        int s = ei[e], d = ei[N_EDGES + e];
        float dx = pos[2 * s] - pos[2 * d];
        float dy = pos[2 * s + 1] - pos[2 * d + 1];
        atomicAdd(&h[branch_idx(dx, dy)], 1);
        atomicAdd(&deg[d], 1);
    }
    __syncthreads();
    if (t < K_BR && h[t] > 0) atomicAdd(&bucketCnt[t], h[t]);
}

__global__ void offsets_kernel(const int* __restrict__ bucketCnt, int* __restrict__ cursor) {
    int off = 0;
    for (int k = 0; k < K_BR; ++k) {
        cursor[k] = off;
        off = (off + bucketCnt[k] + 63) & ~63;  // 64-align next bucket start
    }
}

// ---- hierarchical exclusive scan of deg[N] -> nodeStart[N], nodeCur[N] ----
__global__ void scanA_kernel(const int* __restrict__ deg, int* __restrict__ nodeStart,
                             int* __restrict__ blockSums) {
    __shared__ int s[256];
    int t = threadIdx.x;
    int i = blockIdx.x * 256 + t;
    int v = (i < N_NODES) ? deg[i] : 0;
    s[t] = v;
    __syncthreads();
#pragma unroll
    for (int off = 1; off < 256; off <<= 1) {
        int tmp = (t >= off) ? s[t - off] : 0;
        __syncthreads();
        s[t] += tmp;
        __syncthreads();
    }
    if (i < N_NODES) nodeStart[i] = s[t] - v;  // exclusive
    if (t == 255) blockSums[blockIdx.x] = s[255];
}

__global__ void scanB_kernel(const int* __restrict__ blockSums, int* __restrict__ blockOffs) {
    __shared__ int s[256];
    int t = threadIdx.x;
    int v = (t < SCAN_BLOCKS) ? blockSums[t] : 0;
    s[t] = v;
    __syncthreads();
#pragma unroll
    for (int off = 1; off < 256; off <<= 1) {
        int tmp = (t >= off) ? s[t - off] : 0;
        __syncthreads();
        s[t] += tmp;
        __syncthreads();
    }
    blockOffs[t] = s[t] - v;
}

__global__ void scanC_kernel(int* __restrict__ nodeStart, const int* __restrict__ blockOffs,
                             int* __restrict__ nodeCur) {
    int i = blockIdx.x * 256 + threadIdx.x;
    if (i < N_NODES) {
        int ns = nodeStart[i] + blockOffs[blockIdx.x];
        nodeStart[i] = ns;
        nodeCur[i] = ns;
    }
}

__global__ void scatter_kernel(const int* __restrict__ ei, const float* __restrict__ pos,
                               int* __restrict__ cursor, int* __restrict__ perm,
                               int* __restrict__ nodeCur, int* __restrict__ slotOf, int mode) {
    __shared__ int h[K_BR];
    __shared__ int base[K_BR];
    int t = threadIdx.x;
    if (t < K_BR) h[t] = 0;
    __syncthreads();
    int e = blockIdx.x * blockDim.x + t;
    int idx = 0, rank = 0;
    bool valid = e < N_EDGES;
    if (valid) {
        int s = ei[e], d = ei[N_EDGES + e];
        float dx = pos[2 * s] - pos[2 * d];
        float dy = pos[2 * s + 1] - pos[2 * d + 1];
        idx = branch_idx(dx, dy);
        rank = atomicAdd(&h[idx], 1);
        if (mode) slotOf[e] = atomicAdd(&nodeCur[d], 1);
    }
    __syncthreads();
    if (t < K_BR) base[t] = (h[t] > 0) ? atomicAdd(&cursor[t], h[t]) : 0;
    __syncthreads();
    if (valid) perm[base[idx] + rank] = e | (idx << 24);
}

__global__ void __launch_bounds__(256) mlp_kernel(
    const int* __restrict__ perm, const int* __restrict__ ei,
    const float* __restrict__ x, const float* __restrict__ ea,
    const float* __restrict__ ew,
    const float* __restrict__ W1T, const float* __restrict__ b1,
    const float* __restrict__ W2T, const float* __restrict__ b2,
    float* __restrict__ fbuf, const int* __restrict__ slotOf, int mode) {
    int t = blockIdx.x * blockDim.x + threadIdx.x;
    int p = perm[t];
    // bucket spans are 64-aligned and filled contiguously from the start, so
    // if lane 0 of a wave is padding (-1), the whole wave is padding.
    int p0 = __builtin_amdgcn_readfirstlane(p);
    if (p0 < 0) return;
    int k = (p0 >> 24) & 7;  // wave-uniform branch id -> weights become s_loads
    bool valid = p >= 0;
    int e = valid ? (p & 0xFFFFFF) : (p0 & 0xFFFFFF);

    int s = ei[e];
    int d = ei[N_EDGES + e];

    float m[36];
    const float4* xj = (const float4*)(x + 32 * (size_t)s);
    const float4* xi = (const float4*)(x + 32 * (size_t)d);
#pragma unroll
    for (int q = 0; q < 8; ++q) {
        float4 a = xj[q], b = xi[q];
        m[4 * q + 0] = a.x - b.x;
        m[4 * q + 1] = a.y - b.y;
        m[4 * q + 2] = a.z - b.z;
        m[4 * q + 3] = a.w - b.w;
    }
    float4 eav = ((const float4*)ea)[e];
    m[32] = eav.x; m[33] = eav.y; m[34] = eav.z; m[35] = eav.w;
    float w = ew[e];

    const float* w1  = W1T + k * (32 * 36);
    const float* bb1 = b1 + k * 32;
    float h[32];
#pragma unroll
    for (int o = 0; o < 32; ++o) {
        float acc = bb1[o];
#pragma unroll
        for (int c = 0; c < 36; ++c) acc = fmaf(m[c], w1[o * 36 + c], acc);
        h[o] = fmaxf(acc, 0.0f);
    }

    const float* w2  = W2T + k * 1024;
    const float* bb2 = b2 + k * 32;
    if (mode) {
        int slot = valid ? slotOf[e] : 0;
        float4* frow = (float4*)(fbuf + 32 * (size_t)slot);
#pragma unroll
        for (int go = 0; go < 8; ++go) {
            float4 r;
#pragma unroll
            for (int gi = 0; gi < 4; ++gi) {
                int g = go * 4 + gi;
                float acc = bb2[g];
#pragma unroll
                for (int o = 0; o < 32; ++o) acc = fmaf(h[o], w2[g * 32 + o], acc);
                (&r.x)[gi] = fmaxf(acc, 0.0f) * w;
            }
            if (valid) frow[go] = r;
        }
    } else {
        float* srow = fbuf + 32 * (size_t)d;
#pragma unroll
        for (int g = 0; g < 32; ++g) {
            float acc = bb2[g];
#pragma unroll
            for (int o = 0; o < 32; ++o) acc = fmaf(h[o], w2[g * 32 + o], acc);
            float f = fmaxf(acc, 0.0f) * w;
            if (valid) unsafeAtomicAdd(&srow[g], f);
        }
    }
}

__global__ void agg_kernel(const float* __restrict__ fbuf, const int* __restrict__ nodeStart,
                           const int* __restrict__ deg,
                           const float* __restrict__ x, const float* __restrict__ Wr,
                           const float* __restrict__ br, float* __restrict__ out) {
    int t = blockIdx.x * blockDim.x + threadIdx.x;
    if (t >= N_NODES * 32) return;
    int n = t >> 5, o = t & 31;
    int st = nodeStart[n], dg = deg[n];
    float acc = 0.0f;
    for (int j = 0; j < dg; ++j) acc += fbuf[(size_t)(st + j) * 32 + o];
    float inv = 1.0f / (float)max(dg, 1);
    acc = acc * inv + br[o];
    const float* xr = x + 32 * (size_t)n;
#pragma unroll
    for (int c = 0; c < 32; ++c) acc = fmaf(xr[c], Wr[c * 32 + o], acc);
    out[t] = acc;
}

__global__ void final_atomic_kernel(const float* __restrict__ sum, const int* __restrict__ deg,
                                    const float* __restrict__ x, const float* __restrict__ Wr,
                                    const float* __restrict__ br, float* __restrict__ out) {
    int t = blockIdx.x * blockDim.x + threadIdx.x;
    if (t >= N_NODES * 32) return;
    int n = t >> 5, o = t & 31;
    float inv = 1.0f / (float)max(deg[n], 1);
    float acc = sum[t] * inv + br[o];
    const float* xr = x + 32 * (size_t)n;
#pragma unroll
    for (int c = 0; c < 32; ++c) acc = fmaf(xr[c], Wr[c * 32 + o], acc);
    out[t] = acc;
}

extern "C" void kernel_launch(void* const* d_in, const int* in_sizes, int n_in,
                              void* d_out, int out_size, void* d_ws, size_t ws_size,
                              hipStream_t stream) {
    const float* x   = (const float*)d_in[0];
    const float* pos = (const float*)d_in[1];
    const int*   ei  = (const int*)d_in[2];
    const float* ea  = (const float*)d_in[3];
    const float* ew  = (const float*)d_in[4];
    const float* W1  = (const float*)d_in[5];
    const float* b1  = (const float*)d_in[6];
    const float* W2  = (const float*)d_in[7];
    const float* b2  = (const float*)d_in[8];
    const float* Wr  = (const float*)d_in[9];
    const float* br  = (const float*)d_in[10];
    float* out = (float*)d_out;

    char* ws = (char*)d_ws;
    const size_t FULL_NEED = 109473920;
    int mode = (ws_size >= FULL_NEED) ? 1 : 0;

    if (mode) {
        int*   deg       = (int*)(ws + 0);
        int*   nodeStart = (int*)(ws + 200064);
        int*   nodeCur   = (int*)(ws + 400128);
        int*   blockSums = (int*)(ws + 600128);
        int*   blockOffs = (int*)(ws + 601152);
        int*   bucketCnt = (int*)(ws + 602176);
        int*   bucketCur = (int*)(ws + 602208);
        int*   perm      = (int*)(ws + 602240);
        int*   slotOf    = (int*)(ws + 3804288);
        float* W1T       = (float*)(ws + 7004288);
        float* W2T       = (float*)(ws + 7041152);
        float* fbuf      = (float*)(ws + 7073920);

        hipMemsetAsync(deg, 0, 200064, stream);
        hipMemsetAsync(bucketCnt, 0, 64, stream);
        hipMemsetAsync(perm, 0xFF, (N_EDGES + 512) * 4, stream);

        transpose_kernel<<<68, 256, 0, stream>>>(W1, W2, W1T, W2T);
        count_kernel<<<(N_EDGES + 255) / 256, 256, 0, stream>>>(ei, pos, bucketCnt, deg);
        offsets_kernel<<<1, 1, 0, stream>>>(bucketCnt, bucketCur);
        scanA_kernel<<<SCAN_BLOCKS, 256, 0, stream>>>(deg, nodeStart, blockSums);
        scanB_kernel<<<1, 256, 0, stream>>>(blockSums, blockOffs);
        scanC_kernel<<<SCAN_BLOCKS, 256, 0, stream>>>(nodeStart, blockOffs, nodeCur);
        scatter_kernel<<<(N_EDGES + 255) / 256, 256, 0, stream>>>(ei, pos, bucketCur, perm,
                                                                  nodeCur, slotOf, 1);
        mlp_kernel<<<(N_EDGES + 512) / 256, 256, 0, stream>>>(perm, ei, x, ea, ew,
                                                              W1T, b1, W2T, b2, fbuf, slotOf, 1);
        agg_kernel<<<(N_NODES * 32 + 255) / 256, 256, 0, stream>>>(fbuf, nodeStart, deg,
                                                                   x, Wr, br, out);
    } else {
        // fallback: atomic-scatter variant (round-1 layout)
        float* sum       = (float*)(ws + 0);
        int*   deg       = (int*)(ws + 6400000);
        int*   bucketCnt = (int*)(ws + 6600000);
        int*   bucketCur = (int*)(ws + 6600032);
        int*   perm      = (int*)(ws + 6600064);
        float* W1T       = (float*)(ws + 9802112);
        float* W2T       = (float*)(ws + 9838976);

        hipMemsetAsync(sum, 0, 6600000, stream);
        hipMemsetAsync(bucketCnt, 0, 64, stream);
        hipMemsetAsync(perm, 0xFF, (N_EDGES + 512) * 4, stream);

        transpose_kernel<<<68, 256, 0, stream>>>(W1, W2, W1T, W2T);
        count_kernel<<<(N_EDGES + 255) / 256, 256, 0, stream>>>(ei, pos, bucketCnt, deg);
        offsets_kernel<<<1, 1, 0, stream>>>(bucketCnt, bucketCur);
        scatter_kernel<<<(N_EDGES + 255) / 256, 256, 0, stream>>>(ei, pos, bucketCur, perm,
                                                                  nullptr, nullptr, 0);
        mlp_kernel<<<(N_EDGES + 512) / 256, 256, 0, stream>>>(perm, ei, x, ea, ew,
                                                              W1T, b1, W2T, b2, sum, nullptr, 0);
        final_atomic_kernel<<<(N_NODES * 32 + 255) / 256, 256, 0, stream>>>(sum, deg, x, Wr, br, out);
    }
}